// Round 1
// baseline (144.315 us; speedup 1.0000x reference)
//
#include <hip/hip_runtime.h>
#include <math.h>

#define C 64
#define NB_ERB 32
#define NB_DF 96
#define EMB 256

// d_out layout (fp32, flat concat in return order)
#define OUT_E0      0       // 64*32 = 2048
#define OUT_E1      2048    // 64*16 = 1024
#define OUT_E2      3072    // 64*8  = 512
#define OUT_E3      3584    // 64*4  = 256
#define OUT_EMB     3840    // 256
#define OUT_C0      4096    // 64*96 = 6144
#define OUT_LSNR    10240   // 1
#define OUT_BUF_ERB 10241   // 32
#define OUT_BUF_DF  10273   // 192
#define OUT_HENC    10465   // 256  (total 10721)

// ws layout (floats)
#define WS_GH   0           // 768
#define WS_PART 768         // 48*256 = 12288

static __device__ __forceinline__ float sigm(float x) {
    return 1.0f / (1.0f + expf(-x));
}

// ---------------- K1: everything that depends only on inputs ----------------
// blocks [0,24)   : c0   (6144 outputs, 1 thread each)
// blocks [24,32)  : e0   (2048 outputs, 1 thread each)
// blocks [32,224) : gh   (768 rows, one 64-lane wave per row)
// block  224      : buffer copies
__global__ __launch_bounds__(256) void k1(
    const float* __restrict__ feat_erb, const float* __restrict__ feat_spec,
    const float* __restrict__ buf_erb0, const float* __restrict__ buf_df0,
    const float* __restrict__ h_enc,
    const float* __restrict__ W_erb0, const float* __restrict__ b_erb0,
    const float* __restrict__ W_df0,  const float* __restrict__ b_df0,
    const float* __restrict__ W_hh,   const float* __restrict__ b_hh,
    float* __restrict__ out, float* __restrict__ ws)
{
    const int blk = blockIdx.x, t = threadIdx.x;
    if (blk < 24) {                       // c0[o,w], w=0..95
        int g = blk * 256 + t;
        int o = g / NB_DF, w = g % NB_DF;
        float acc = b_df0[o];
        const float* W = W_df0 + o * 12;  // [c][kt][kw]
        #pragma unroll
        for (int c = 0; c < 2; ++c)
            #pragma unroll
            for (int kw = 0; kw < 3; ++kw) {
                int x = w + kw - 1;
                if (x >= 0 && x < NB_DF) {
                    acc += W[c * 6 + kw]     * buf_df0[c * NB_DF + x];   // kt=0
                    acc += W[c * 6 + 3 + kw] * feat_spec[c * NB_DF + x]; // kt=1
                }
            }
        out[OUT_C0 + g] = fmaxf(acc, 0.0f);
    } else if (blk < 32) {                // e0[o,w], w=0..31
        int g = (blk - 24) * 256 + t;
        int o = g / NB_ERB, w = g % NB_ERB;
        float acc = b_erb0[o];
        const float* W = W_erb0 + o * 6;  // [kt][kw]
        #pragma unroll
        for (int kw = 0; kw < 3; ++kw) {
            int x = w + kw - 1;
            if (x >= 0 && x < NB_ERB) {
                acc += W[kw]     * buf_erb0[x];  // kt=0
                acc += W[3 + kw] * feat_erb[x];  // kt=1
            }
        }
        out[OUT_E0 + g] = fmaxf(acc, 0.0f);
    } else if (blk < 224) {               // gh: one wave per output row
        int o = (blk - 32) * 4 + (t >> 6);
        int lane = t & 63;
        const float4 wv = *reinterpret_cast<const float4*>(W_hh + o * EMB + lane * 4);
        const float4 hv = *reinterpret_cast<const float4*>(h_enc + lane * 4);
        float a = wv.x * hv.x + wv.y * hv.y + wv.z * hv.z + wv.w * hv.w;
        #pragma unroll
        for (int off = 32; off; off >>= 1) a += __shfl_down(a, off);
        if (lane == 0) ws[WS_GH + o] = a + b_hh[o];
    } else {                              // buffer passthrough outputs
        if (t < 32)  out[OUT_BUF_ERB + t] = feat_erb[t];
        if (t < 192) out[OUT_BUF_DF + t]  = feat_spec[t];
    }
}

// ---------------- K2: second stage -------------------------------------------
// block 0     : e1 -> e2 -> e3 (serial chain, LDS-staged activations+weights)
// blocks 1..48: c1 column (w = blk-1) + W_dffc partial product into ws
__global__ __launch_bounds__(256) void k2(
    const float* __restrict__ W_erb1, const float* __restrict__ b_erb1,
    const float* __restrict__ W_erb2, const float* __restrict__ b_erb2,
    const float* __restrict__ W_erb3, const float* __restrict__ b_erb3,
    const float* __restrict__ W_df1,  const float* __restrict__ b_df1,
    const float* __restrict__ W_dffc,
    float* __restrict__ out, float* __restrict__ ws)
{
    const int blk = blockIdx.x, t = threadIdx.x;
    if (blk == 0) {
        // LDS: padded weights (stride 193 breaks the stride-192 bank pattern),
        // e0 (2048), e1 (1024); e2 reuses the e0 buffer.
        __shared__ float sW[64 * 193];
        __shared__ float sA[2048];   // e0, then e2 (512)
        __shared__ float sB[1024];   // e1

        for (int k = t; k < 2048; k += 256) sA[k] = out[OUT_E0 + k];
        for (int k = t; k < 12288; k += 256) sW[(k / 192) * 193 + (k % 192)] = W_erb1[k];
        __syncthreads();

        // ---- e1: 1024 outputs, thread t -> o=t&63, w = wg*4+q (wg=t>>6) ----
        const int o = t & 63, wg = t >> 6;
        {
            float a0 = b_erb1[o], a1 = a0, a2 = a0, a3 = a0;
            for (int i = 0; i < 64; ++i) {
                float w0 = sW[o * 193 + i * 3 + 0];
                float w1 = sW[o * 193 + i * 3 + 1];
                float w2 = sW[o * 193 + i * 3 + 2];
                const float* e = &sA[i * 32];
                int xb = wg * 8 - 1;                 // x for (q=0,kw=0)
                float ev[9];
                #pragma unroll
                for (int m = 0; m < 9; ++m) {
                    int x = xb + m;
                    ev[m] = (x >= 0) ? e[x] : 0.0f;  // wave-uniform guard
                }
                a0 += w0 * ev[0] + w1 * ev[1] + w2 * ev[2];
                a1 += w0 * ev[2] + w1 * ev[3] + w2 * ev[4];
                a2 += w0 * ev[4] + w1 * ev[5] + w2 * ev[6];
                a3 += w0 * ev[6] + w1 * ev[7] + w2 * ev[8];
            }
            a0 = fmaxf(a0, 0.0f); a1 = fmaxf(a1, 0.0f);
            a2 = fmaxf(a2, 0.0f); a3 = fmaxf(a3, 0.0f);
            int w = wg * 4;
            out[OUT_E1 + o * 16 + w + 0] = a0; sB[o * 16 + w + 0] = a0;
            out[OUT_E1 + o * 16 + w + 1] = a1; sB[o * 16 + w + 1] = a1;
            out[OUT_E1 + o * 16 + w + 2] = a2; sB[o * 16 + w + 2] = a2;
            out[OUT_E1 + o * 16 + w + 3] = a3; sB[o * 16 + w + 3] = a3;
        }
        __syncthreads();
        for (int k = t; k < 12288; k += 256) sW[(k / 192) * 193 + (k % 192)] = W_erb2[k];
        __syncthreads();

        // ---- e2: 512 outputs, thread t -> o=t&63, w in {2*wg, 2*wg+1} ----
        {
            float a0 = b_erb2[o], a1 = a0;
            for (int i = 0; i < 64; ++i) {
                float w0 = sW[o * 193 + i * 3 + 0];
                float w1 = sW[o * 193 + i * 3 + 1];
                float w2 = sW[o * 193 + i * 3 + 2];
                const float* e = &sB[i * 16];
                int xb = 4 * wg - 1;
                float v0 = (xb >= 0) ? e[xb] : 0.0f;
                float v1 = e[xb + 1], v2 = e[xb + 2], v3 = e[xb + 3], v4 = e[xb + 4];
                a0 += w0 * v0 + w1 * v1 + w2 * v2;
                a1 += w0 * v2 + w1 * v3 + w2 * v4;
            }
            a0 = fmaxf(a0, 0.0f); a1 = fmaxf(a1, 0.0f);
            __syncthreads();   // sA (e0) fully consumed by e1 phase above
            int w = 2 * wg;
            out[OUT_E2 + o * 8 + w + 0] = a0; sA[o * 8 + w + 0] = a0;
            out[OUT_E2 + o * 8 + w + 1] = a1; sA[o * 8 + w + 1] = a1;
        }
        __syncthreads();
        for (int k = t; k < 12288; k += 256) sW[(k / 192) * 193 + (k % 192)] = W_erb3[k];
        __syncthreads();

        // ---- e3: 256 outputs, thread t -> o=t&63, w=wg ----
        {
            float a = b_erb3[o];
            for (int i = 0; i < 64; ++i) {
                float w0 = sW[o * 193 + i * 3 + 0];
                float w1 = sW[o * 193 + i * 3 + 1];
                float w2 = sW[o * 193 + i * 3 + 2];
                const float* e = &sA[i * 8];
                int xb = 2 * wg - 1;
                float v0 = (xb >= 0) ? e[xb] : 0.0f;
                a += w0 * v0 + w1 * e[xb + 1] + w2 * e[xb + 2];
            }
            out[OUT_E3 + o * 4 + wg] = fmaxf(a, 0.0f);
        }
    } else {
        // ---- c1 column w = blk-1, then partial cemb contribution ----
        const int w = blk - 1;
        __shared__ float s_c1[64];
        const int c = t >> 2, p = t & 3;
        float acc = 0.0f;
        const float* c0p = out + OUT_C0;
        for (int ii = 0; ii < 16; ++ii) {
            int i = p * 16 + ii;
            const float* Wr = W_df1 + c * 192 + i * 3;
            const float* cr = c0p + i * NB_DF;
            #pragma unroll
            for (int kw = 0; kw < 3; ++kw) {
                int x = 2 * w + kw - 1;
                if (x >= 0) acc += Wr[kw] * cr[x];   // x<=95 always
            }
        }
        acc += __shfl_down(acc, 2, 4);
        acc += __shfl_down(acc, 1, 4);
        if (p == 0) s_c1[c] = fmaxf(acc + b_df1[c], 0.0f);
        __syncthreads();
        // thread t = output o: dot(W_dffc[o, w*64 : w*64+64], c1col)
        {
            const float4* Wp = reinterpret_cast<const float4*>(W_dffc + t * 3072 + w * 64);
            float a = 0.0f;
            #pragma unroll
            for (int q = 0; q < 16; ++q) {
                float4 v = Wp[q];
                a += v.x * s_c1[q * 4 + 0] + v.y * s_c1[q * 4 + 1]
                   + v.z * s_c1[q * 4 + 2] + v.w * s_c1[q * 4 + 3];
            }
            ws[WS_PART + w * 256 + t] = a;   // coalesced write
        }
    }
}

// ---------------- K3: cemb finalize + GRU + lsnr (single block) --------------
__global__ __launch_bounds__(1024) void k3(
    const float* __restrict__ h_enc, const float* __restrict__ b_dffc,
    const float* __restrict__ W_ih,  const float* __restrict__ b_ih,
    const float* __restrict__ W_lsnr, const float* __restrict__ b_lsnr,
    float* __restrict__ out, float* __restrict__ ws)
{
    const int t = threadIdx.x;
    __shared__ __align__(16) float s_x2[256];
    __shared__ float s_h2[256];
    __shared__ float s_gi[768];
    __shared__ float s_hn[256];

    if (t < 256) {
        float acc = b_dffc[t];
        for (int w = 0; w < 48; ++w) acc += ws[WS_PART + w * 256 + t]; // coalesced rows
        float cemb = fmaxf(acc, 0.0f);
        // x2[j], j = w*64 + c  ->  e3[c, w] at OUT_E3 + c*4 + w
        float e3v = out[OUT_E3 + (t & 63) * 4 + (t >> 6)];
        s_x2[t] = e3v + cemb;
        s_h2[t] = h_enc[t];
    }
    __syncthreads();

    // gi: one wave per row triple (o, o+256, o+512) reuses x fragment
    const int wv = t >> 6, lane = t & 63;
    const float4 xv = *reinterpret_cast<const float4*>(&s_x2[lane * 4]);
    for (int o = wv; o < 256; o += 16) {
        const float4 wr = *reinterpret_cast<const float4*>(W_ih + (o      ) * 256 + lane * 4);
        const float4 wz = *reinterpret_cast<const float4*>(W_ih + (o + 256) * 256 + lane * 4);
        const float4 wn = *reinterpret_cast<const float4*>(W_ih + (o + 512) * 256 + lane * 4);
        float ar = wr.x * xv.x + wr.y * xv.y + wr.z * xv.z + wr.w * xv.w;
        float az = wz.x * xv.x + wz.y * xv.y + wz.z * xv.z + wz.w * xv.w;
        float an = wn.x * xv.x + wn.y * xv.y + wn.z * xv.z + wn.w * xv.w;
        #pragma unroll
        for (int off = 32; off; off >>= 1) {
            ar += __shfl_down(ar, off);
            az += __shfl_down(az, off);
            an += __shfl_down(an, off);
        }
        if (lane == 0) {
            s_gi[o      ] = ar + b_ih[o      ];
            s_gi[o + 256] = az + b_ih[o + 256];
            s_gi[o + 512] = an + b_ih[o + 512];
        }
    }
    __syncthreads();

    if (t < 256) {
        float r  = sigm(s_gi[t      ] + ws[WS_GH + t      ]);
        float z  = sigm(s_gi[256 + t] + ws[WS_GH + 256 + t]);
        float ng = tanhf(s_gi[512 + t] + r * ws[WS_GH + 512 + t]);
        float h  = (1.0f - z) * ng + z * s_h2[t];
        out[OUT_EMB  + t] = h;
        out[OUT_HENC + t] = h;
        s_hn[t] = h * W_lsnr[t];
    }
    __syncthreads();

    if (t < 64) {
        float a = s_hn[t] + s_hn[64 + t] + s_hn[128 + t] + s_hn[192 + t];
        #pragma unroll
        for (int off = 32; off; off >>= 1) a += __shfl_down(a, off);
        if (t == 0)
            out[OUT_LSNR] = sigm(a + b_lsnr[0]) * 50.0f - 15.0f;
    }
}

extern "C" void kernel_launch(void* const* d_in, const int* in_sizes, int n_in,
                              void* d_out, int out_size, void* d_ws, size_t ws_size,
                              hipStream_t stream) {
    (void)in_sizes; (void)n_in; (void)out_size; (void)ws_size;
    const float* feat_erb  = (const float*)d_in[0];
    const float* feat_spec = (const float*)d_in[1];
    const float* buf_erb0  = (const float*)d_in[2];
    const float* buf_df0   = (const float*)d_in[3];
    const float* h_enc     = (const float*)d_in[4];
    const float* W_erb0    = (const float*)d_in[5];
    const float* b_erb0    = (const float*)d_in[6];
    const float* W_erb1    = (const float*)d_in[7];
    const float* b_erb1    = (const float*)d_in[8];
    const float* W_erb2    = (const float*)d_in[9];
    const float* b_erb2    = (const float*)d_in[10];
    const float* W_erb3    = (const float*)d_in[11];
    const float* b_erb3    = (const float*)d_in[12];
    const float* W_df0     = (const float*)d_in[13];
    const float* b_df0     = (const float*)d_in[14];
    const float* W_df1     = (const float*)d_in[15];
    const float* b_df1     = (const float*)d_in[16];
    const float* W_dffc    = (const float*)d_in[17];
    const float* b_dffc    = (const float*)d_in[18];
    const float* W_ih      = (const float*)d_in[19];
    const float* b_ih      = (const float*)d_in[20];
    const float* W_hh      = (const float*)d_in[21];
    const float* b_hh      = (const float*)d_in[22];
    const float* W_lsnr    = (const float*)d_in[23];
    const float* b_lsnr    = (const float*)d_in[24];
    float* out = (float*)d_out;
    float* ws  = (float*)d_ws;

    hipLaunchKernelGGL(k1, dim3(225), dim3(256), 0, stream,
                       feat_erb, feat_spec, buf_erb0, buf_df0, h_enc,
                       W_erb0, b_erb0, W_df0, b_df0, W_hh, b_hh, out, ws);
    hipLaunchKernelGGL(k2, dim3(49), dim3(256), 0, stream,
                       W_erb1, b_erb1, W_erb2, b_erb2, W_erb3, b_erb3,
                       W_df1, b_df1, W_dffc, out, ws);
    hipLaunchKernelGGL(k3, dim3(1), dim3(1024), 0, stream,
                       h_enc, b_dffc, W_ih, b_ih, W_lsnr, b_lsnr, out, ws);
}

// Round 3
// 125.980 us; speedup vs baseline: 1.1455x; 1.1455x over previous
//
#include <hip/hip_runtime.h>
#include <math.h>

#define NB_ERB 32
#define NB_DF 96
#define EMB 256

// d_out layout (fp32, flat concat in return order)
#define OUT_E0      0       // 2048
#define OUT_E1      2048    // 1024
#define OUT_E2      3072    // 512
#define OUT_E3      3584    // 256
#define OUT_EMB     3840    // 256
#define OUT_C0      4096    // 6144
#define OUT_LSNR    10240   // 1
#define OUT_BUF_ERB 10241   // 32
#define OUT_BUF_DF  10273   // 192
#define OUT_HENC    10465   // 256  (total 10721)

// ws layout (floats)
#define WS_GH   0           // 768
#define WS_PART 768         // 48*256

static __device__ __forceinline__ float sigm(float x) {
    return 1.0f / (1.0f + expf(-x));
}

// ---------------- K1: everything that depends only on inputs ----------------
// blocks [0,24)  : c0 (6144 outs)
// blocks [24,32) : e0 (2048 outs)
// blocks [32,80) : gh (768 rows; 4 waves/block, 4 rows/wave)
// block  80      : buffer passthrough copies
__global__ __launch_bounds__(256) void k1(
    const float* __restrict__ feat_erb, const float* __restrict__ feat_spec,
    const float* __restrict__ buf_erb0, const float* __restrict__ buf_df0,
    const float* __restrict__ h_enc,
    const float* __restrict__ W_erb0, const float* __restrict__ b_erb0,
    const float* __restrict__ W_df0,  const float* __restrict__ b_df0,
    const float* __restrict__ W_hh,   const float* __restrict__ b_hh,
    float* __restrict__ out, float* __restrict__ ws)
{
    const int blk = blockIdx.x, t = threadIdx.x;
    if (blk < 24) {                       // c0[o,w]
        int g = blk * 256 + t;
        int o = g / NB_DF, w = g % NB_DF;
        float acc = b_df0[o];
        const float* W = W_df0 + o * 12;  // [c][kt][kw]
        #pragma unroll
        for (int c = 0; c < 2; ++c)
            #pragma unroll
            for (int kw = 0; kw < 3; ++kw) {
                int x = w + kw - 1;
                if (x >= 0 && x < NB_DF) {
                    acc += W[c * 6 + kw]     * buf_df0[c * NB_DF + x];
                    acc += W[c * 6 + 3 + kw] * feat_spec[c * NB_DF + x];
                }
            }
        out[OUT_C0 + g] = fmaxf(acc, 0.0f);
    } else if (blk < 32) {                // e0[o,w]
        int g = (blk - 24) * 256 + t;
        int o = g / NB_ERB, w = g % NB_ERB;
        float acc = b_erb0[o];
        const float* W = W_erb0 + o * 6;
        #pragma unroll
        for (int kw = 0; kw < 3; ++kw) {
            int x = w + kw - 1;
            if (x >= 0 && x < NB_ERB) {
                acc += W[kw]     * buf_erb0[x];
                acc += W[3 + kw] * feat_erb[x];
            }
        }
        out[OUT_E0 + g] = fmaxf(acc, 0.0f);
    } else if (blk < 80) {                // gh: 4 rows per wave
        const int wv = t >> 6, lane = t & 63;
        const int o0 = (blk - 32) * 16 + wv * 4;
        const float4 hv = *reinterpret_cast<const float4*>(h_enc + lane * 4);
        float r[4];
        #pragma unroll
        for (int j = 0; j < 4; ++j) {
            const float4 wr = *reinterpret_cast<const float4*>(W_hh + (o0 + j) * EMB + lane * 4);
            r[j] = wr.x * hv.x + wr.y * hv.y + wr.z * hv.z + wr.w * hv.w;
        }
        #pragma unroll
        for (int off = 32; off; off >>= 1) {
            #pragma unroll
            for (int j = 0; j < 4; ++j) r[j] += __shfl_down(r[j], off);
        }
        if (lane == 0) {
            #pragma unroll
            for (int j = 0; j < 4; ++j) ws[WS_GH + o0 + j] = r[j] + b_hh[o0 + j];
        }
    } else {                              // buffer passthrough
        if (t < 32)  out[OUT_BUF_ERB + t] = feat_erb[t];
        if (t < 192) out[OUT_BUF_DF + t]  = feat_spec[t];
    }
}

// ---------------- K2: second stage -------------------------------------------
// block 0     : e1 -> e2 -> e3 (pipelined weight staging, LDS convs)
// blocks 1..48: c1 column (w = blk-1) + W_dffc partial into ws
__global__ __launch_bounds__(256) void k2(
    const float* __restrict__ W_erb1, const float* __restrict__ b_erb1,
    const float* __restrict__ W_erb2, const float* __restrict__ b_erb2,
    const float* __restrict__ W_erb3, const float* __restrict__ b_erb3,
    const float* __restrict__ W_df1,  const float* __restrict__ b_df1,
    const float* __restrict__ W_dffc,
    float* __restrict__ out, float* __restrict__ ws)
{
    const int blk = blockIdx.x, t = threadIdx.x;
    __shared__ float sW1[64 * 193];   // stride 193: conflict-free weight reads
    __shared__ float sW2[64 * 193];
    __shared__ __align__(16) float sA[2048];  // e0, later e2 (512)
    __shared__ __align__(16) float sB[1024];  // e1
    __shared__ float s_c0[192];
    __shared__ float s_c1[64];

    if (blk == 0) {
        const int o = t & 63, wg = t >> 6;   // wg is wave-uniform
        float4 wbuf[12];

        // stage W1 (reg->LDS) + e0, then issue W2 loads before the barrier
        {
            const float4* W1v = reinterpret_cast<const float4*>(W_erb1);
            #pragma unroll
            for (int j = 0; j < 12; ++j) wbuf[j] = W1v[t + 256 * j];
            const float4* e0v = reinterpret_cast<const float4*>(out + OUT_E0);
            float4 a0 = e0v[t], a1 = e0v[t + 256];
            reinterpret_cast<float4*>(sA)[t]       = a0;
            reinterpret_cast<float4*>(sA)[t + 256] = a1;
            #pragma unroll
            for (int j = 0; j < 12; ++j) {
                int k4 = t + 256 * j;
                float* p = &sW1[(k4 / 48) * 193 + (k4 % 48) * 4];
                p[0] = wbuf[j].x; p[1] = wbuf[j].y; p[2] = wbuf[j].z; p[3] = wbuf[j].w;
            }
            const float4* W2v = reinterpret_cast<const float4*>(W_erb2);
            #pragma unroll
            for (int j = 0; j < 12; ++j) wbuf[j] = W2v[t + 256 * j];
        }
        __syncthreads();

        // ---- e1: o=t&63, w = wg*4+q ----
        {
            float bias = b_erb1[o];
            float a0 = bias, a1 = bias, a2 = bias, a3 = bias;
            const float* wrow = &sW1[o * 193];
            for (int i = 0; i < 64; ++i) {
                float w0 = wrow[i * 3], w1 = wrow[i * 3 + 1], w2 = wrow[i * 3 + 2];
                const float* e = &sA[i * 32 + wg * 8];
                float em1 = (wg == 0) ? 0.0f : e[-1];     // wave-uniform branch
                float4 v0 = *reinterpret_cast<const float4*>(e);
                float4 v1 = *reinterpret_cast<const float4*>(e + 4);
                a0 += w0 * em1  + w1 * v0.x + w2 * v0.y;
                a1 += w0 * v0.y + w1 * v0.z + w2 * v0.w;
                a2 += w0 * v0.w + w1 * v1.x + w2 * v1.y;
                a3 += w0 * v1.y + w1 * v1.z + w2 * v1.w;
            }
            float4 r = make_float4(fmaxf(a0, 0.f), fmaxf(a1, 0.f),
                                   fmaxf(a2, 0.f), fmaxf(a3, 0.f));
            reinterpret_cast<float4*>(&sB[o * 16])[wg] = r;
            reinterpret_cast<float4*>(out + OUT_E1)[o * 4 + wg] = r;
        }
        // write W2 to LDS, issue W3 loads
        {
            #pragma unroll
            for (int j = 0; j < 12; ++j) {
                int k4 = t + 256 * j;
                float* p = &sW2[(k4 / 48) * 193 + (k4 % 48) * 4];
                p[0] = wbuf[j].x; p[1] = wbuf[j].y; p[2] = wbuf[j].z; p[3] = wbuf[j].w;
            }
            const float4* W3v = reinterpret_cast<const float4*>(W_erb3);
            #pragma unroll
            for (int j = 0; j < 12; ++j) wbuf[j] = W3v[t + 256 * j];
        }
        __syncthreads();

        // ---- e2: w in {2wg, 2wg+1} ----
        {
            float bias = b_erb2[o];
            float a0 = bias, a1 = bias;
            const float* wrow = &sW2[o * 193];
            for (int i = 0; i < 64; ++i) {
                float w0 = wrow[i * 3], w1 = wrow[i * 3 + 1], w2 = wrow[i * 3 + 2];
                const float* e = &sB[i * 16 + wg * 4];
                float em1 = (wg == 0) ? 0.0f : e[-1];
                float4 v = *reinterpret_cast<const float4*>(e);
                a0 += w0 * em1 + w1 * v.x + w2 * v.y;
                a1 += w0 * v.y + w1 * v.z + w2 * v.w;
            }
            a0 = fmaxf(a0, 0.0f); a1 = fmaxf(a1, 0.0f);
            int w = 2 * wg;
            sA[o * 8 + w] = a0; sA[o * 8 + w + 1] = a1;   // e2 region (sA reads done pre-sync2)
            out[OUT_E2 + o * 8 + w] = a0; out[OUT_E2 + o * 8 + w + 1] = a1;
        }
        // write W3 to LDS (sW1 free: last read pre-sync2)
        {
            #pragma unroll
            for (int j = 0; j < 12; ++j) {
                int k4 = t + 256 * j;
                float* p = &sW1[(k4 / 48) * 193 + (k4 % 48) * 4];
                p[0] = wbuf[j].x; p[1] = wbuf[j].y; p[2] = wbuf[j].z; p[3] = wbuf[j].w;
            }
        }
        __syncthreads();

        // ---- e3: w = wg ----
        {
            float a = b_erb3[o];
            const float* wrow = &sW1[o * 193];
            for (int i = 0; i < 64; ++i) {
                float w0 = wrow[i * 3], w1 = wrow[i * 3 + 1], w2 = wrow[i * 3 + 2];
                const float* e = &sA[i * 8 + 2 * wg];
                float em1 = (wg == 0) ? 0.0f : e[-1];
                a += w0 * em1 + w1 * e[0] + w2 * e[1];
            }
            out[OUT_E3 + o * 4 + wg] = fmaxf(a, 0.0f);
        }
    } else {
        // ---- c1 column w = blk-1, then partial cemb contribution ----
        const int w = blk - 1;
        const float* c0p = out + OUT_C0;
        if (t < 192) {                        // stage the 3 needed c0 columns
            int i = t / 3, kw = t % 3, x = 2 * w + kw - 1;
            s_c0[t] = (x >= 0) ? c0p[i * NB_DF + x] : 0.0f;
        }
        __syncthreads();
        const int c = t >> 2, p = t & 3;
        float wloc[48];
        {
            const float4* Wv = reinterpret_cast<const float4*>(W_df1 + c * 192 + p * 48);
            #pragma unroll
            for (int q = 0; q < 12; ++q) {
                float4 v = Wv[q];
                wloc[4 * q] = v.x; wloc[4 * q + 1] = v.y;
                wloc[4 * q + 2] = v.z; wloc[4 * q + 3] = v.w;
            }
        }
        float acc = 0.0f;
        #pragma unroll
        for (int ii = 0; ii < 16; ++ii) {
            int i = p * 16 + ii;
            acc += wloc[ii * 3]     * s_c0[i * 3]
                 + wloc[ii * 3 + 1] * s_c0[i * 3 + 1]
                 + wloc[ii * 3 + 2] * s_c0[i * 3 + 2];
        }
        acc += __shfl_down(acc, 2, 4);
        acc += __shfl_down(acc, 1, 4);
        if (p == 0) s_c1[c] = fmaxf(acc + b_df1[c], 0.0f);
        __syncthreads();
        // thread t = output o: dot(W_dffc[o, w*64 : (w+1)*64], c1col)
        {
            const float4* Wp = reinterpret_cast<const float4*>(W_dffc + t * 3072 + w * 64);
            float a = 0.0f;
            #pragma unroll
            for (int q = 0; q < 16; ++q) {
                float4 v = Wp[q];
                a += v.x * s_c1[q * 4]     + v.y * s_c1[q * 4 + 1]
                   + v.z * s_c1[q * 4 + 2] + v.w * s_c1[q * 4 + 3];
            }
            ws[WS_PART + w * 256 + t] = a;
        }
    }
}

// ---------------- K3: cemb finalize + gi + GRU (64 blocks) -------------------
// each block recomputes x2 (cheap, L2-resident) and owns 4 GRU row-triples
__global__ __launch_bounds__(256) void k3(
    const float* __restrict__ h_enc, const float* __restrict__ b_dffc,
    const float* __restrict__ W_ih,  const float* __restrict__ b_ih,
    float* __restrict__ out, float* __restrict__ ws)
{
    const int t = threadIdx.x, blk = blockIdx.x;
    __shared__ __align__(16) float s_x2[256];
    {
        float acc = b_dffc[t];
        #pragma unroll 8
        for (int w = 0; w < 48; ++w) acc += ws[WS_PART + w * 256 + t];
        float cemb = fmaxf(acc, 0.0f);
        float e3v = out[OUT_E3 + (t & 63) * 4 + (t >> 6)];
        s_x2[t] = e3v + cemb;
    }
    __syncthreads();
    const int wv = t >> 6, lane = t & 63;
    const int o = blk * 4 + wv;
    const float4 xv = *reinterpret_cast<const float4*>(&s_x2[lane * 4]);
    const float4 wr = *reinterpret_cast<const float4*>(W_ih + (o      ) * EMB + lane * 4);
    const float4 wz = *reinterpret_cast<const float4*>(W_ih + (o + 256) * EMB + lane * 4);
    const float4 wn = *reinterpret_cast<const float4*>(W_ih + (o + 512) * EMB + lane * 4);
    float ar = wr.x * xv.x + wr.y * xv.y + wr.z * xv.z + wr.w * xv.w;
    float az = wz.x * xv.x + wz.y * xv.y + wz.z * xv.z + wz.w * xv.w;
    float an = wn.x * xv.x + wn.y * xv.y + wn.z * xv.z + wn.w * xv.w;
    #pragma unroll
    for (int off = 32; off; off >>= 1) {
        ar += __shfl_down(ar, off);
        az += __shfl_down(az, off);
        an += __shfl_down(an, off);
    }
    if (lane == 0) {
        float r  = sigm(ar + b_ih[o]       + ws[WS_GH + o]);
        float z  = sigm(az + b_ih[o + 256] + ws[WS_GH + 256 + o]);
        float ng = tanhf(an + b_ih[o + 512] + r * ws[WS_GH + 512 + o]);
        float h  = (1.0f - z) * ng + z * h_enc[o];
        out[OUT_EMB  + o] = h;
        out[OUT_HENC + o] = h;
    }
}

// ---------------- K4: lsnr ---------------------------------------------------
__global__ __launch_bounds__(256) void k4(
    const float* __restrict__ W_lsnr, const float* __restrict__ b_lsnr,
    float* __restrict__ out)
{
    const int t = threadIdx.x;
    __shared__ float s[4];
    float v = out[OUT_EMB + t] * W_lsnr[t];
    #pragma unroll
    for (int off = 32; off; off >>= 1) v += __shfl_down(v, off);
    if ((t & 63) == 0) s[t >> 6] = v;
    __syncthreads();
    if (t == 0)
        out[OUT_LSNR] = sigm(s[0] + s[1] + s[2] + s[3] + b_lsnr[0]) * 50.0f - 15.0f;
}

extern "C" void kernel_launch(void* const* d_in, const int* in_sizes, int n_in,
                              void* d_out, int out_size, void* d_ws, size_t ws_size,
                              hipStream_t stream) {
    (void)in_sizes; (void)n_in; (void)out_size; (void)ws_size;
    const float* feat_erb  = (const float*)d_in[0];
    const float* feat_spec = (const float*)d_in[1];
    const float* buf_erb0  = (const float*)d_in[2];
    const float* buf_df0   = (const float*)d_in[3];
    const float* h_enc     = (const float*)d_in[4];
    const float* W_erb0    = (const float*)d_in[5];
    const float* b_erb0    = (const float*)d_in[6];
    const float* W_erb1    = (const float*)d_in[7];
    const float* b_erb1    = (const float*)d_in[8];
    const float* W_erb2    = (const float*)d_in[9];
    const float* b_erb2    = (const float*)d_in[10];
    const float* W_erb3    = (const float*)d_in[11];
    const float* b_erb3    = (const float*)d_in[12];
    const float* W_df0     = (const float*)d_in[13];
    const float* b_df0     = (const float*)d_in[14];
    const float* W_df1     = (const float*)d_in[15];
    const float* b_df1     = (const float*)d_in[16];
    const float* W_dffc    = (const float*)d_in[17];
    const float* b_dffc    = (const float*)d_in[18];
    const float* W_ih      = (const float*)d_in[19];
    const float* b_ih      = (const float*)d_in[20];
    const float* W_hh      = (const float*)d_in[21];
    const float* b_hh      = (const float*)d_in[22];
    const float* W_lsnr    = (const float*)d_in[23];
    const float* b_lsnr    = (const float*)d_in[24];
    float* out = (float*)d_out;
    float* ws  = (float*)d_ws;

    hipLaunchKernelGGL(k1, dim3(81), dim3(256), 0, stream,
                       feat_erb, feat_spec, buf_erb0, buf_df0, h_enc,
                       W_erb0, b_erb0, W_df0, b_df0, W_hh, b_hh, out, ws);
    hipLaunchKernelGGL(k2, dim3(49), dim3(256), 0, stream,
                       W_erb1, b_erb1, W_erb2, b_erb2, W_erb3, b_erb3,
                       W_df1, b_df1, W_dffc, out, ws);
    hipLaunchKernelGGL(k3, dim3(64), dim3(256), 0, stream,
                       h_enc, b_dffc, W_ih, b_ih, out, ws);
    hipLaunchKernelGGL(k4, dim3(1), dim3(256), 0, stream,
                       W_lsnr, b_lsnr, out);
}

// Round 4
// 123.371 us; speedup vs baseline: 1.1698x; 1.0211x over previous
//
#include <hip/hip_runtime.h>
#include <math.h>

#define NB_ERB 32
#define NB_DF 96
#define EMB 256

// d_out layout (fp32, flat concat in return order)
#define OUT_E0      0       // 2048
#define OUT_E1      2048    // 1024
#define OUT_E2      3072    // 512
#define OUT_E3      3584    // 256
#define OUT_EMB     3840    // 256
#define OUT_C0      4096    // 6144
#define OUT_LSNR    10240   // 1
#define OUT_BUF_ERB 10241   // 32
#define OUT_BUF_DF  10273   // 192
#define OUT_HENC    10465   // 256  (total 10721)

// ws layout (floats)
#define WS_PART 0           // 48*256 partial cemb products

static __device__ __forceinline__ float sigm(float x) {
    return 1.0f / (1.0f + expf(-x));
}

// ---------------- KA: both conv chains ---------------------------------------
// block 0     : e0 (in-block) -> e1 -> e2 -> e3 (pipelined weight staging)
// blocks 1..48: c0 (3 cols, in-block) -> c1 column -> W_dffc partial into ws
__global__ __launch_bounds__(256) void ka(
    const float* __restrict__ feat_erb, const float* __restrict__ feat_spec,
    const float* __restrict__ buf_erb0, const float* __restrict__ buf_df0,
    const float* __restrict__ W_erb0, const float* __restrict__ b_erb0,
    const float* __restrict__ W_erb1, const float* __restrict__ b_erb1,
    const float* __restrict__ W_erb2, const float* __restrict__ b_erb2,
    const float* __restrict__ W_erb3, const float* __restrict__ b_erb3,
    const float* __restrict__ W_df0,  const float* __restrict__ b_df0,
    const float* __restrict__ W_df1,  const float* __restrict__ b_df1,
    const float* __restrict__ W_dffc,
    float* __restrict__ out, float* __restrict__ ws)
{
    const int blk = blockIdx.x, t = threadIdx.x;
    __shared__ float sW1[64 * 193];   // stride 193: conflict-free weight reads
    __shared__ float sW2[64 * 193];
    __shared__ __align__(16) float sA[2048];  // e0, later e2 (512)
    __shared__ __align__(16) float sB[1024];  // e1
    __shared__ float s_c0[192];
    __shared__ float s_c1[64];

    if (blk == 0) {
        const int o = t & 63, wg = t >> 6;   // wg is wave-uniform
        float4 wbuf[12];

        // issue W1 HBM loads first; e0 computes under them
        {
            const float4* W1v = reinterpret_cast<const float4*>(W_erb1);
            #pragma unroll
            for (int j = 0; j < 12; ++j) wbuf[j] = W1v[t + 256 * j];
        }
        // ---- e0 in-block: thread t -> channel oc=t>>2, w in [8q, 8q+8) ----
        {
            const int oc = t >> 2, q = t & 3;
            const float* W = W_erb0 + oc * 6;
            const float b0 = b_erb0[oc];
            #pragma unroll
            for (int m = 0; m < 8; ++m) {
                int w_ = q * 8 + m;
                float a = b0;
                #pragma unroll
                for (int kw = 0; kw < 3; ++kw) {
                    int x = w_ + kw - 1;
                    if (x >= 0 && x < NB_ERB)
                        a += W[kw] * buf_erb0[x] + W[3 + kw] * feat_erb[x];
                }
                float v = fmaxf(a, 0.0f);
                sA[oc * 32 + w_] = v;
                out[OUT_E0 + oc * 32 + w_] = v;
            }
        }
        if (t < 32) out[OUT_BUF_ERB + t] = feat_erb[t];
        // store W1 to LDS, issue W2 loads
        {
            #pragma unroll
            for (int j = 0; j < 12; ++j) {
                int k4 = t + 256 * j;
                float* p = &sW1[(k4 / 48) * 193 + (k4 % 48) * 4];
                p[0] = wbuf[j].x; p[1] = wbuf[j].y; p[2] = wbuf[j].z; p[3] = wbuf[j].w;
            }
            const float4* W2v = reinterpret_cast<const float4*>(W_erb2);
            #pragma unroll
            for (int j = 0; j < 12; ++j) wbuf[j] = W2v[t + 256 * j];
        }
        __syncthreads();

        // ---- e1: o=t&63, w = wg*4+q ----
        {
            float bias = b_erb1[o];
            float a0 = bias, a1 = bias, a2 = bias, a3 = bias;
            const float* wrow = &sW1[o * 193];
            for (int i = 0; i < 64; ++i) {
                float w0 = wrow[i * 3], w1 = wrow[i * 3 + 1], w2 = wrow[i * 3 + 2];
                const float* e = &sA[i * 32 + wg * 8];
                float em1 = (wg == 0) ? 0.0f : e[-1];     // wave-uniform branch
                float4 v0 = *reinterpret_cast<const float4*>(e);
                float4 v1 = *reinterpret_cast<const float4*>(e + 4);
                a0 += w0 * em1  + w1 * v0.x + w2 * v0.y;
                a1 += w0 * v0.y + w1 * v0.z + w2 * v0.w;
                a2 += w0 * v0.w + w1 * v1.x + w2 * v1.y;
                a3 += w0 * v1.y + w1 * v1.z + w2 * v1.w;
            }
            float4 r = make_float4(fmaxf(a0, 0.f), fmaxf(a1, 0.f),
                                   fmaxf(a2, 0.f), fmaxf(a3, 0.f));
            reinterpret_cast<float4*>(&sB[o * 16])[wg] = r;
            reinterpret_cast<float4*>(out + OUT_E1)[o * 4 + wg] = r;
        }
        // write W2 to LDS, issue W3 loads
        {
            #pragma unroll
            for (int j = 0; j < 12; ++j) {
                int k4 = t + 256 * j;
                float* p = &sW2[(k4 / 48) * 193 + (k4 % 48) * 4];
                p[0] = wbuf[j].x; p[1] = wbuf[j].y; p[2] = wbuf[j].z; p[3] = wbuf[j].w;
            }
            const float4* W3v = reinterpret_cast<const float4*>(W_erb3);
            #pragma unroll
            for (int j = 0; j < 12; ++j) wbuf[j] = W3v[t + 256 * j];
        }
        __syncthreads();

        // ---- e2: w in {2wg, 2wg+1} ----
        {
            float bias = b_erb2[o];
            float a0 = bias, a1 = bias;
            const float* wrow = &sW2[o * 193];
            for (int i = 0; i < 64; ++i) {
                float w0 = wrow[i * 3], w1 = wrow[i * 3 + 1], w2 = wrow[i * 3 + 2];
                const float* e = &sB[i * 16 + wg * 4];
                float em1 = (wg == 0) ? 0.0f : e[-1];
                float4 v = *reinterpret_cast<const float4*>(e);
                a0 += w0 * em1 + w1 * v.x + w2 * v.y;
                a1 += w0 * v.y + w1 * v.z + w2 * v.w;
            }
            a0 = fmaxf(a0, 0.0f); a1 = fmaxf(a1, 0.0f);
            int w = 2 * wg;
            sA[o * 8 + w] = a0; sA[o * 8 + w + 1] = a1;   // e0 fully consumed pre-barrier
            out[OUT_E2 + o * 8 + w] = a0; out[OUT_E2 + o * 8 + w + 1] = a1;
        }
        // write W3 to LDS (sW1 free: last read before previous barrier)
        {
            #pragma unroll
            for (int j = 0; j < 12; ++j) {
                int k4 = t + 256 * j;
                float* p = &sW1[(k4 / 48) * 193 + (k4 % 48) * 4];
                p[0] = wbuf[j].x; p[1] = wbuf[j].y; p[2] = wbuf[j].z; p[3] = wbuf[j].w;
            }
        }
        __syncthreads();

        // ---- e3: w = wg ----
        {
            float a = b_erb3[o];
            const float* wrow = &sW1[o * 193];
            for (int i = 0; i < 64; ++i) {
                float w0 = wrow[i * 3], w1 = wrow[i * 3 + 1], w2 = wrow[i * 3 + 2];
                const float* e = &sA[i * 8 + 2 * wg];
                float em1 = (wg == 0) ? 0.0f : e[-1];
                a += w0 * em1 + w1 * e[0] + w2 * e[1];
            }
            out[OUT_E3 + o * 4 + wg] = fmaxf(a, 0.0f);
        }
    } else {
        // ---- blocks 1..48: c0 (3 needed cols) -> c1 col w -> cemb partial ----
        const int w = blk - 1;
        if (blk == 1 && t < 192) out[OUT_BUF_DF + t] = feat_spec[t];
        if (t < 192) {
            const int i = t & 63, j = t >> 6;     // j = 0..2, X = 2w-1+j
            const int X = 2 * w - 1 + j;
            float v = 0.0f;
            if (X >= 0) {                          // X <= 95 always
                float acc = b_df0[i];
                const float* Wp = W_df0 + i * 12;  // [c][kt][kw]
                #pragma unroll
                for (int c = 0; c < 2; ++c)
                    #pragma unroll
                    for (int kw = 0; kw < 3; ++kw) {
                        int x = X + kw - 1;
                        if (x >= 0 && x < NB_DF) {
                            acc += Wp[c * 6 + kw]     * buf_df0[c * NB_DF + x];
                            acc += Wp[c * 6 + 3 + kw] * feat_spec[c * NB_DF + x];
                        }
                    }
                v = fmaxf(acc, 0.0f);
                if (j >= 1) out[OUT_C0 + i * NB_DF + X] = v;  // cols 2w, 2w+1
            }
            s_c0[i * 3 + j] = v;
        }
        __syncthreads();
        const int c = t >> 2, p = t & 3;
        float wloc[48];
        {
            const float4* Wv = reinterpret_cast<const float4*>(W_df1 + c * 192 + p * 48);
            #pragma unroll
            for (int q = 0; q < 12; ++q) {
                float4 v = Wv[q];
                wloc[4 * q] = v.x; wloc[4 * q + 1] = v.y;
                wloc[4 * q + 2] = v.z; wloc[4 * q + 3] = v.w;
            }
        }
        float acc = 0.0f;
        #pragma unroll
        for (int ii = 0; ii < 16; ++ii) {
            int i = p * 16 + ii;
            acc += wloc[ii * 3]     * s_c0[i * 3]
                 + wloc[ii * 3 + 1] * s_c0[i * 3 + 1]
                 + wloc[ii * 3 + 2] * s_c0[i * 3 + 2];
        }
        acc += __shfl_down(acc, 2, 4);
        acc += __shfl_down(acc, 1, 4);
        if (p == 0) s_c1[c] = fmaxf(acc + b_df1[c], 0.0f);
        __syncthreads();
        // thread t = output o: dot(W_dffc[o, w*64 : (w+1)*64], c1col)
        {
            const float4* Wp = reinterpret_cast<const float4*>(W_dffc + t * 3072 + w * 64);
            float a = 0.0f;
            #pragma unroll
            for (int q = 0; q < 16; ++q) {
                float4 v = Wp[q];
                a += v.x * s_c1[q * 4]     + v.y * s_c1[q * 4 + 1]
                   + v.z * s_c1[q * 4 + 2] + v.w * s_c1[q * 4 + 3];
            }
            ws[WS_PART + w * 256 + t] = a;
        }
    }
}

// ---------------- KB: x2 + gi + gh + GRU (64 blocks) -------------------------
// each block recomputes x2 (L2-resident partials); each wave owns one output o
// and computes all 6 dot-256 products (gi r/z/n + gh r/z/n) itself.
__global__ __launch_bounds__(256) void kb(
    const float* __restrict__ h_enc, const float* __restrict__ b_dffc,
    const float* __restrict__ W_ih,  const float* __restrict__ b_ih,
    const float* __restrict__ W_hh,  const float* __restrict__ b_hh,
    float* __restrict__ out, const float* __restrict__ ws)
{
    const int t = threadIdx.x, blk = blockIdx.x;
    __shared__ __align__(16) float s_x2[256];
    {
        float acc = b_dffc[t];
        #pragma unroll 8
        for (int w = 0; w < 48; ++w) acc += ws[WS_PART + w * 256 + t];
        float cemb = fmaxf(acc, 0.0f);
        float e3v = out[OUT_E3 + (t & 63) * 4 + (t >> 6)];
        s_x2[t] = e3v + cemb;
    }
    __syncthreads();
    const int wv = t >> 6, lane = t & 63;
    const int o = blk * 4 + wv;
    const float4 xv = *reinterpret_cast<const float4*>(&s_x2[lane * 4]);
    const float4 hv = *reinterpret_cast<const float4*>(h_enc + lane * 4);
    const float4 wir = *reinterpret_cast<const float4*>(W_ih + (o      ) * EMB + lane * 4);
    const float4 wiz = *reinterpret_cast<const float4*>(W_ih + (o + 256) * EMB + lane * 4);
    const float4 win = *reinterpret_cast<const float4*>(W_ih + (o + 512) * EMB + lane * 4);
    const float4 whr = *reinterpret_cast<const float4*>(W_hh + (o      ) * EMB + lane * 4);
    const float4 whz = *reinterpret_cast<const float4*>(W_hh + (o + 256) * EMB + lane * 4);
    const float4 whn = *reinterpret_cast<const float4*>(W_hh + (o + 512) * EMB + lane * 4);
    float air = wir.x * xv.x + wir.y * xv.y + wir.z * xv.z + wir.w * xv.w;
    float aiz = wiz.x * xv.x + wiz.y * xv.y + wiz.z * xv.z + wiz.w * xv.w;
    float ain = win.x * xv.x + win.y * xv.y + win.z * xv.z + win.w * xv.w;
    float ahr = whr.x * hv.x + whr.y * hv.y + whr.z * hv.z + whr.w * hv.w;
    float ahz = whz.x * hv.x + whz.y * hv.y + whz.z * hv.z + whz.w * hv.w;
    float ahn = whn.x * hv.x + whn.y * hv.y + whn.z * hv.z + whn.w * hv.w;
    #pragma unroll
    for (int off = 32; off; off >>= 1) {
        air += __shfl_down(air, off);
        aiz += __shfl_down(aiz, off);
        ain += __shfl_down(ain, off);
        ahr += __shfl_down(ahr, off);
        ahz += __shfl_down(ahz, off);
        ahn += __shfl_down(ahn, off);
    }
    if (lane == 0) {
        float r  = sigm(air + b_ih[o]       + ahr + b_hh[o]);
        float z  = sigm(aiz + b_ih[o + 256] + ahz + b_hh[o + 256]);
        float ng = tanhf(ain + b_ih[o + 512] + r * (ahn + b_hh[o + 512]));
        float h  = (1.0f - z) * ng + z * h_enc[o];
        out[OUT_EMB  + o] = h;
        out[OUT_HENC + o] = h;
    }
}

// ---------------- KC: lsnr ---------------------------------------------------
__global__ __launch_bounds__(256) void kc(
    const float* __restrict__ W_lsnr, const float* __restrict__ b_lsnr,
    float* __restrict__ out)
{
    const int t = threadIdx.x;
    __shared__ float s[4];
    float v = out[OUT_EMB + t] * W_lsnr[t];
    #pragma unroll
    for (int off = 32; off; off >>= 1) v += __shfl_down(v, off);
    if ((t & 63) == 0) s[t >> 6] = v;
    __syncthreads();
    if (t == 0)
        out[OUT_LSNR] = sigm(s[0] + s[1] + s[2] + s[3] + b_lsnr[0]) * 50.0f - 15.0f;
}

extern "C" void kernel_launch(void* const* d_in, const int* in_sizes, int n_in,
                              void* d_out, int out_size, void* d_ws, size_t ws_size,
                              hipStream_t stream) {
    (void)in_sizes; (void)n_in; (void)out_size; (void)ws_size;
    const float* feat_erb  = (const float*)d_in[0];
    const float* feat_spec = (const float*)d_in[1];
    const float* buf_erb0  = (const float*)d_in[2];
    const float* buf_df0   = (const float*)d_in[3];
    const float* h_enc     = (const float*)d_in[4];
    const float* W_erb0    = (const float*)d_in[5];
    const float* b_erb0    = (const float*)d_in[6];
    const float* W_erb1    = (const float*)d_in[7];
    const float* b_erb1    = (const float*)d_in[8];
    const float* W_erb2    = (const float*)d_in[9];
    const float* b_erb2    = (const float*)d_in[10];
    const float* W_erb3    = (const float*)d_in[11];
    const float* b_erb3    = (const float*)d_in[12];
    const float* W_df0     = (const float*)d_in[13];
    const float* b_df0     = (const float*)d_in[14];
    const float* W_df1     = (const float*)d_in[15];
    const float* b_df1     = (const float*)d_in[16];
    const float* W_dffc    = (const float*)d_in[17];
    const float* b_dffc    = (const float*)d_in[18];
    const float* W_ih      = (const float*)d_in[19];
    const float* b_ih      = (const float*)d_in[20];
    const float* W_hh      = (const float*)d_in[21];
    const float* b_hh      = (const float*)d_in[22];
    const float* W_lsnr    = (const float*)d_in[23];
    const float* b_lsnr    = (const float*)d_in[24];
    float* out = (float*)d_out;
    float* ws  = (float*)d_ws;

    hipLaunchKernelGGL(ka, dim3(49), dim3(256), 0, stream,
                       feat_erb, feat_spec, buf_erb0, buf_df0,
                       W_erb0, b_erb0, W_erb1, b_erb1, W_erb2, b_erb2,
                       W_erb3, b_erb3, W_df0, b_df0, W_df1, b_df1,
                       W_dffc, out, ws);
    hipLaunchKernelGGL(kb, dim3(64), dim3(256), 0, stream,
                       h_enc, b_dffc, W_ih, b_ih, W_hh, b_hh, out, ws);
    hipLaunchKernelGGL(kc, dim3(1), dim3(256), 0, stream,
                       W_lsnr, b_lsnr, out);
}